// Round 7
// baseline (381.928 us; speedup 1.0000x reference)
//
#include <hip/hip_runtime.h>
#include <math.h>

#define DIMC 256
#define NH 8
#define NPIX 16384          // 128*128
#define BATCH 16
#define ATT_SCALE 0.17677669529663687f   // 1/sqrt(32)
#define LN_EPS 1e-5f
#define NSLAB 32            // n-slabs per batch (512 n each)

// ---------------------------------------------------------------------------
// K0: qkT[b][c][h] = SCALE * sum_d q[b][h*32+d] * Wkv[h*32+d][c]
// Layout [c][h] so k_fused can read 8 h contiguously at uniform address.
// ---------------------------------------------------------------------------
__global__ __launch_bounds__(256) void k_qk(const float* __restrict__ audio,
                                            const float* __restrict__ Wq,
                                            const float* __restrict__ Wkv,
                                            float* __restrict__ qkT) {
    int b = blockIdx.x;
    int t = threadIdx.x;
    __shared__ float aud[DIMC];
    __shared__ float qL[DIMC];
    aud[t] = audio[b * DIMC + t];
    __syncthreads();
    {
        const float* wr = Wq + (size_t)t * DIMC;
        float acc = 0.f;
        for (int c = 0; c < DIMC; c += 4) {
            float4 w = *(const float4*)(wr + c);
            acc = fmaf(w.x, aud[c], acc);
            acc = fmaf(w.y, aud[c + 1], acc);
            acc = fmaf(w.z, aud[c + 2], acc);
            acc = fmaf(w.w, aud[c + 3], acc);
        }
        qL[t] = acc;
    }
    __syncthreads();
    {
        int c = t;
        float acc = 0.f;
        for (int i = 0; i < DIMC; ++i) {
            acc = fmaf(qL[i], Wkv[(size_t)i * DIMC + c], acc);
            if ((i & 31) == 31) {
                qkT[((size_t)b * DIMC + c) * NH + (i >> 5)] = ATT_SCALE * acc;
                acc = 0.f;
            }
        }
    }
}

// ---------------------------------------------------------------------------
// K1 fused attn + s. 512 blocks x 256 thr (2 blk/CU, 8 waves/CU).
// Block owns (b, 512-n slab).
//  Phase 1: thread owns 2 n; loop 256 c with coalesced float2 loads (fm from
//           HBM, 512B/wave-instr); qkT wave-uniform -> s_load. spike -> aL
//           (16 KB LDS, [h][512]).
//  Phase 2: thread owns c = t; re-reads the SAME 512-KB fm slab (L3-resident,
//           L1-line amortized rows) x wave-uniform aL broadcasts; writes
//           s_part[b][slab][h][c] directly (no cross-thread reduce).
// Only __syncthreads() for sync — no inline-asm barriers.
// ---------------------------------------------------------------------------
__global__ __launch_bounds__(256) void k_fused(const float* __restrict__ fm,
                                               const float* __restrict__ qkT,
                                               float* __restrict__ s_part) {
    __shared__ float aL[NH * 512];     // 16 KB

    const int blk  = blockIdx.x;       // b*32 + slab
    const int b    = blk >> 5;
    const int slab = blk & 31;
    const int t    = threadIdx.x;
    const int n0   = slab * 512;

    // ---- phase 1: attn + spike for this slab's 512 n ----
    {
        const int n_l = t * 2;
        const float* fmb = fm + (size_t)b * DIMC * NPIX + n0 + n_l;
        const float* qb  = qkT + (size_t)b * DIMC * NH;

        float a0[NH], a1[NH];
#pragma unroll
        for (int h = 0; h < NH; ++h) { a0[h] = 0.f; a1[h] = 0.f; }

#pragma unroll 4
        for (int c = 0; c < DIMC; ++c) {
            float2 v  = *(const float2*)(fmb + (size_t)c * NPIX);
            float4 q0 = *(const float4*)(qb + c * NH);       // uniform -> s_load
            float4 q1 = *(const float4*)(qb + c * NH + 4);
            a0[0] = fmaf(v.x, q0.x, a0[0]); a1[0] = fmaf(v.y, q0.x, a1[0]);
            a0[1] = fmaf(v.x, q0.y, a0[1]); a1[1] = fmaf(v.y, q0.y, a1[1]);
            a0[2] = fmaf(v.x, q0.z, a0[2]); a1[2] = fmaf(v.y, q0.z, a1[2]);
            a0[3] = fmaf(v.x, q0.w, a0[3]); a1[3] = fmaf(v.y, q0.w, a1[3]);
            a0[4] = fmaf(v.x, q1.x, a0[4]); a1[4] = fmaf(v.y, q1.x, a1[4]);
            a0[5] = fmaf(v.x, q1.y, a0[5]); a1[5] = fmaf(v.y, q1.y, a1[5]);
            a0[6] = fmaf(v.x, q1.z, a0[6]); a1[6] = fmaf(v.y, q1.z, a1[6]);
            a0[7] = fmaf(v.x, q1.w, a0[7]); a1[7] = fmaf(v.y, q1.w, a1[7]);
        }

#pragma unroll
        for (int h = 0; h < NH; ++h) {
            float2 o;
            o.x = rintf(fminf(fmaxf(a0[h], 0.f), 4.f)) * 0.25f;
            o.y = rintf(fminf(fmaxf(a1[h], 0.f), 4.f)) * 0.25f;
            *(float2*)(aL + h * 512 + n_l) = o;
        }
    }
    __syncthreads();

    // ---- phase 2: s[c][h] over this slab; fm slab re-read (L3) ----
    {
        const int c = t;
        const float* fr = fm + ((size_t)b * DIMC + c) * NPIX + n0;

        float acc[NH];
#pragma unroll
        for (int h = 0; h < NH; ++h) acc[h] = 0.f;

#pragma unroll 2
        for (int ng = 0; ng < 128; ++ng) {
            float4 v = *(const float4*)(fr + ng * 4);
#pragma unroll
            for (int h = 0; h < NH; ++h) {
                float4 av = *(const float4*)(aL + h * 512 + ng * 4);  // broadcast
                acc[h] += fmaf(v.x, av.x, fmaf(v.y, av.y, fmaf(v.z, av.z, v.w * av.w)));
            }
        }

#pragma unroll
        for (int h = 0; h < NH; ++h)
            s_part[(((size_t)b * NSLAB + slab) * NH + h) * DIMC + c] = acc[h];
    }
}

// ---------------------------------------------------------------------------
// K2: s = sum_slab s_part ; x = Wv*s ; p = Wp*x + bp ; LN ; spike -> scale
// ---------------------------------------------------------------------------
__global__ __launch_bounds__(256) void k_scale(const float* __restrict__ s_part,
                                               const float* __restrict__ Wkv,
                                               const float* __restrict__ Wp,
                                               const float* __restrict__ bp,
                                               const float* __restrict__ g,
                                               const float* __restrict__ beta,
                                               float* __restrict__ scale) {
    int b = blockIdx.x;
    int t = threadIdx.x;
    __shared__ float sL[NH][DIMC];
    __shared__ float xL[DIMC];
    __shared__ float red[8];
    __shared__ float mu_s, var_s;

    for (int h = 0; h < NH; ++h) {
        float acc = 0.f;
        for (int sl = 0; sl < NSLAB; ++sl)
            acc += s_part[(((size_t)b * NSLAB + sl) * NH + h) * DIMC + t];
        sL[h][t] = acc;
    }
    __syncthreads();

    {
        const float* wr = Wkv + (size_t)(DIMC + t) * DIMC;
        const float* sr = sL[t >> 5];
        float acc = 0.f;
        for (int cc = 0; cc < DIMC; cc += 4) {
            float4 w = *(const float4*)(wr + cc);
            acc = fmaf(w.x, sr[cc], acc);
            acc = fmaf(w.y, sr[cc + 1], acc);
            acc = fmaf(w.z, sr[cc + 2], acc);
            acc = fmaf(w.w, sr[cc + 3], acc);
        }
        xL[t] = acc;
    }
    __syncthreads();

    float p;
    {
        const float* wr = Wp + (size_t)t * DIMC;
        float acc = 0.f;
        for (int i = 0; i < DIMC; i += 4) {
            float4 w = *(const float4*)(wr + i);
            acc = fmaf(w.x, xL[i], acc);
            acc = fmaf(w.y, xL[i + 1], acc);
            acc = fmaf(w.z, xL[i + 2], acc);
            acc = fmaf(w.w, xL[i + 3], acc);
        }
        p = acc + bp[t];
    }

    int lane = t & 63, wid = t >> 6;
    float r = p;
#pragma unroll
    for (int off = 32; off > 0; off >>= 1) r += __shfl_down(r, off);
    if (lane == 0) red[wid] = r;
    __syncthreads();
    if (t == 0) mu_s = (red[0] + red[1] + red[2] + red[3]) * (1.f / 256.f);
    __syncthreads();
    float mu = mu_s;
    float dd = p - mu;
    float r2 = dd * dd;
#pragma unroll
    for (int off = 32; off > 0; off >>= 1) r2 += __shfl_down(r2, off);
    if (lane == 0) red[4 + wid] = r2;
    __syncthreads();
    if (t == 0) var_s = (red[4] + red[5] + red[6] + red[7]) * (1.f / 256.f);
    __syncthreads();

    float ln = dd * (1.0f / sqrtf(var_s + LN_EPS)) * g[t] + beta[t];
    scale[b * DIMC + t] = rintf(fminf(fmaxf(ln, 0.f), 4.f)) * 0.25f;
}

// ---------------------------------------------------------------------------
// K3: out = fm * scale[b][c]
// ---------------------------------------------------------------------------
__global__ __launch_bounds__(256) void k_out(const float* __restrict__ fm,
                                             const float* __restrict__ scale,
                                             float* __restrict__ out) {
    const size_t total4 = (size_t)BATCH * DIMC * NPIX / 4;
    size_t stride = (size_t)gridDim.x * blockDim.x;
    size_t gid = (size_t)blockIdx.x * blockDim.x + threadIdx.x;
    for (size_t i = gid; i < total4; i += stride) {
        float4 v = *(const float4*)(fm + i * 4);
        float sval = scale[i >> 12];
        float4 o;
        o.x = v.x * sval; o.y = v.y * sval; o.z = v.z * sval; o.w = v.w * sval;
        *(float4*)(out + i * 4) = o;
    }
}

// ---------------------------------------------------------------------------
extern "C" void kernel_launch(void* const* d_in, const int* in_sizes, int n_in,
                              void* d_out, int out_size, void* d_ws, size_t ws_size,
                              hipStream_t stream) {
    (void)in_sizes; (void)n_in; (void)out_size; (void)ws_size;
    const float* fm    = (const float*)d_in[0];
    const float* audio = (const float*)d_in[1];
    const float* Wq    = (const float*)d_in[2];
    const float* Wkv   = (const float*)d_in[3];
    const float* Wp    = (const float*)d_in[4];
    const float* bp    = (const float*)d_in[5];
    const float* g     = (const float*)d_in[6];
    const float* beta  = (const float*)d_in[7];
    float* out = (float*)d_out;

    char* ws = (char*)d_ws;
    float* qkT    = (float*)(ws);                                   // 128 KB
    float* s_part = (float*)(ws + (size_t)131072);                  // 4 MB
    float* scale  = (float*)(ws + (size_t)131072 + 4194304);        // 16 KB

    hipLaunchKernelGGL(k_qk,    dim3(BATCH),      dim3(256), 0, stream, audio, Wq, Wkv, qkT);
    hipLaunchKernelGGL(k_fused, dim3(512),        dim3(256), 0, stream, fm, qkT, s_part);
    hipLaunchKernelGGL(k_scale, dim3(BATCH),      dim3(256), 0, stream, s_part, Wkv, Wp, bp, g, beta, scale);
    hipLaunchKernelGGL(k_out,   dim3(2048),       dim3(256), 0, stream, fm, scale, out);
}

// Round 8
// 316.413 us; speedup vs baseline: 1.2071x; 1.2071x over previous
//
#include <hip/hip_runtime.h>
#include <math.h>

#define DIMC 256
#define NH 8
#define NPIX 16384          // 128*128
#define BATCH 16
#define ATT_SCALE 0.17677669529663687f   // 1/sqrt(32)
#define LN_EPS 1e-5f
#define NBLK_S 4            // n-splits in k_s
#define NCQ 2               // c-splits in K_A

// ---------------------------------------------------------------------------
// K0: qkT[b][c][h] = SCALE * sum_d q[b][h*32+d] * Wkv[h*32+d][c]
// ---------------------------------------------------------------------------
__global__ __launch_bounds__(256) void k_qk(const float* __restrict__ audio,
                                            const float* __restrict__ Wq,
                                            const float* __restrict__ Wkv,
                                            float* __restrict__ qkT) {
    int b = blockIdx.x;
    int t = threadIdx.x;
    __shared__ float aud[DIMC];
    __shared__ float qL[DIMC];
    aud[t] = audio[b * DIMC + t];
    __syncthreads();
    {
        const float* wr = Wq + (size_t)t * DIMC;
        float acc = 0.f;
        for (int c = 0; c < DIMC; c += 4) {
            float4 w = *(const float4*)(wr + c);
            acc = fmaf(w.x, aud[c], acc);
            acc = fmaf(w.y, aud[c + 1], acc);
            acc = fmaf(w.z, aud[c + 2], acc);
            acc = fmaf(w.w, aud[c + 3], acc);
        }
        qL[t] = acc;
    }
    __syncthreads();
    {
        int c = t;
        float acc = 0.f;
        for (int i = 0; i < DIMC; ++i) {
            acc = fmaf(qL[i], Wkv[(size_t)i * DIMC + c], acc);
            if ((i & 31) == 31) {
                qkT[((size_t)b * DIMC + c) * NH + (i >> 5)] = ATT_SCALE * acc;
                acc = 0.f;
            }
        }
    }
}

// ---------------------------------------------------------------------------
// K_A: attn partials, c-split x2. 512 blocks x 256 thr. NO LDS, NO barriers.
// Block = (b, nblk of 1024 n, cq of 128 c). Thread owns 4 consecutive n
// (float4 coalesced, 1 KB/wave-instr); loops 128 c, unroll 8 -> ~8 float4
// loads in flight per wave. qkT reads wave-uniform -> s_load.
// part[cq][b][h][n] += fm[b][c][n] * qkT[b][c][h]
// ---------------------------------------------------------------------------
__global__ __launch_bounds__(256) void k_attnA(const float* __restrict__ fm,
                                               const float* __restrict__ qkT,
                                               float* __restrict__ part) {
    const int blk  = blockIdx.x;          // b*32 + nblk*2 + cq
    const int b    = blk >> 5;
    const int nblk = (blk >> 1) & 15;
    const int cq   = blk & 1;
    const int t    = threadIdx.x;

    const int n0 = nblk * 1024 + t * 4;
    const int c0 = cq * 128;
    const float* fmb = fm + ((size_t)b * DIMC + c0) * NPIX + n0;
    const float* qb  = qkT + ((size_t)b * DIMC + c0) * NH;

    float4 acc[NH];
#pragma unroll
    for (int h = 0; h < NH; ++h) acc[h] = (float4){0.f, 0.f, 0.f, 0.f};

#pragma unroll 8
    for (int c = 0; c < 128; ++c) {
        float4 v  = *(const float4*)(fmb + (size_t)c * NPIX);
        float4 q0 = *(const float4*)(qb + c * NH);        // uniform -> s_load
        float4 q1 = *(const float4*)(qb + c * NH + 4);
        acc[0].x = fmaf(v.x, q0.x, acc[0].x); acc[0].y = fmaf(v.y, q0.x, acc[0].y);
        acc[0].z = fmaf(v.z, q0.x, acc[0].z); acc[0].w = fmaf(v.w, q0.x, acc[0].w);
        acc[1].x = fmaf(v.x, q0.y, acc[1].x); acc[1].y = fmaf(v.y, q0.y, acc[1].y);
        acc[1].z = fmaf(v.z, q0.y, acc[1].z); acc[1].w = fmaf(v.w, q0.y, acc[1].w);
        acc[2].x = fmaf(v.x, q0.z, acc[2].x); acc[2].y = fmaf(v.y, q0.z, acc[2].y);
        acc[2].z = fmaf(v.z, q0.z, acc[2].z); acc[2].w = fmaf(v.w, q0.z, acc[2].w);
        acc[3].x = fmaf(v.x, q0.w, acc[3].x); acc[3].y = fmaf(v.y, q0.w, acc[3].y);
        acc[3].z = fmaf(v.z, q0.w, acc[3].z); acc[3].w = fmaf(v.w, q0.w, acc[3].w);
        acc[4].x = fmaf(v.x, q1.x, acc[4].x); acc[4].y = fmaf(v.y, q1.x, acc[4].y);
        acc[4].z = fmaf(v.z, q1.x, acc[4].z); acc[4].w = fmaf(v.w, q1.x, acc[4].w);
        acc[5].x = fmaf(v.x, q1.y, acc[5].x); acc[5].y = fmaf(v.y, q1.y, acc[5].y);
        acc[5].z = fmaf(v.z, q1.y, acc[5].z); acc[5].w = fmaf(v.w, q1.y, acc[5].w);
        acc[6].x = fmaf(v.x, q1.z, acc[6].x); acc[6].y = fmaf(v.y, q1.z, acc[6].y);
        acc[6].z = fmaf(v.z, q1.z, acc[6].z); acc[6].w = fmaf(v.w, q1.z, acc[6].w);
        acc[7].x = fmaf(v.x, q1.w, acc[7].x); acc[7].y = fmaf(v.y, q1.w, acc[7].y);
        acc[7].z = fmaf(v.z, q1.w, acc[7].z); acc[7].w = fmaf(v.w, q1.w, acc[7].w);
    }

#pragma unroll
    for (int h = 0; h < NH; ++h)
        *(float4*)(part + (((size_t)cq * BATCH + b) * NH + h) * NPIX + n0) = acc[h];
}

// ---------------------------------------------------------------------------
// K_B: a = spike(part0 + part1), written in-place over part0.
// 2048 blocks x 256 thr, one float4 per thread. Pure streaming.
// ---------------------------------------------------------------------------
__global__ __launch_bounds__(256) void k_attnB(float* __restrict__ part) {
    const size_t gid = (size_t)blockIdx.x * 256 + threadIdx.x;   // 524288
    const size_t off = gid * 4;
    const size_t stride_cq = (size_t)BATCH * NH * NPIX;          // 2M floats
    float4 p0 = *(const float4*)(part + off);
    float4 p1 = *(const float4*)(part + stride_cq + off);
    float4 o;
    o.x = rintf(fminf(fmaxf(p0.x + p1.x, 0.f), 4.f)) * 0.25f;
    o.y = rintf(fminf(fmaxf(p0.y + p1.y, 0.f), 4.f)) * 0.25f;
    o.z = rintf(fminf(fmaxf(p0.z + p1.z, 0.f), 4.f)) * 0.25f;
    o.w = rintf(fminf(fmaxf(p0.w + p1.w, 0.f), 4.f)) * 0.25f;
    *(float4*)(part + off) = o;    // a[b][h][n] aliases part[cq=0]
}

// ---------------------------------------------------------------------------
// K_S: s partials. 1024 blocks (XCD-bijective swizzle), 256 thr (4 blk/CU).
// Thread = (c_local 16, nq 16): owns one c, strides n by 64.
// ---------------------------------------------------------------------------
__global__ __launch_bounds__(256) void k_s(const float* __restrict__ fm,
                                           const float* __restrict__ a,
                                           float* __restrict__ s_part) {
    int d    = blockIdx.x;
    int blk  = (d & 7) * 128 + (d >> 3);   // bijective: 1024 = 8 x 128
    int b    = blk >> 6;
    int nblk = (blk >> 4) & 3;
    int cblk = blk & 15;
    int t    = threadIdx.x;
    int c_l  = t >> 4;
    int nq   = t & 15;
    int c    = cblk * 16 + c_l;

    const float* fr = fm + ((size_t)b * DIMC + c) * NPIX + nblk * 4096 + nq * 4;
    const float* ab = a + (size_t)b * NH * NPIX + nblk * 4096 + nq * 4;

    float acc[NH];
#pragma unroll
    for (int h = 0; h < NH; ++h) acc[h] = 0.f;

#pragma unroll 2
    for (int j = 0; j < 64; ++j) {
        float4 v = *(const float4*)(fr + j * 64);
#pragma unroll
        for (int h = 0; h < NH; ++h) {
            float4 av = *(const float4*)(ab + (size_t)h * NPIX + j * 64);
            acc[h] += fmaf(v.x, av.x, fmaf(v.y, av.y, fmaf(v.z, av.z, v.w * av.w)));
        }
    }

    __shared__ float red[256 * NH];    // 8 KB
#pragma unroll
    for (int h = 0; h < NH; ++h) red[t * NH + h] = acc[h];
    __syncthreads();

    if (t < 128) {
        int cl = t >> 3, h = t & 7;
        float sum = 0.f;
#pragma unroll
        for (int q = 0; q < 16; ++q)
            sum += red[(cl * 16 + q) * NH + h];
        s_part[(((size_t)b * NBLK_S + nblk) * NH + h) * DIMC + cblk * 16 + cl] = sum;
    }
}

// ---------------------------------------------------------------------------
// K_scale: s = sum_slab s_part ; x = Wv*s ; p = Wp*x + bp ; LN ; spike
// ---------------------------------------------------------------------------
__global__ __launch_bounds__(256) void k_scale(const float* __restrict__ s_part,
                                               const float* __restrict__ Wkv,
                                               const float* __restrict__ Wp,
                                               const float* __restrict__ bp,
                                               const float* __restrict__ g,
                                               const float* __restrict__ beta,
                                               float* __restrict__ scale) {
    int b = blockIdx.x;
    int t = threadIdx.x;
    __shared__ float sL[NH][DIMC];
    __shared__ float xL[DIMC];
    __shared__ float red[8];
    __shared__ float mu_s, var_s;

    for (int h = 0; h < NH; ++h) {
        float acc = 0.f;
        for (int sl = 0; sl < NBLK_S; ++sl)
            acc += s_part[(((size_t)b * NBLK_S + sl) * NH + h) * DIMC + t];
        sL[h][t] = acc;
    }
    __syncthreads();

    {
        const float* wr = Wkv + (size_t)(DIMC + t) * DIMC;
        const float* sr = sL[t >> 5];
        float acc = 0.f;
        for (int cc = 0; cc < DIMC; cc += 4) {
            float4 w = *(const float4*)(wr + cc);
            acc = fmaf(w.x, sr[cc], acc);
            acc = fmaf(w.y, sr[cc + 1], acc);
            acc = fmaf(w.z, sr[cc + 2], acc);
            acc = fmaf(w.w, sr[cc + 3], acc);
        }
        xL[t] = acc;
    }
    __syncthreads();

    float p;
    {
        const float* wr = Wp + (size_t)t * DIMC;
        float acc = 0.f;
        for (int i = 0; i < DIMC; i += 4) {
            float4 w = *(const float4*)(wr + i);
            acc = fmaf(w.x, xL[i], acc);
            acc = fmaf(w.y, xL[i + 1], acc);
            acc = fmaf(w.z, xL[i + 2], acc);
            acc = fmaf(w.w, xL[i + 3], acc);
        }
        p = acc + bp[t];
    }

    int lane = t & 63, wid = t >> 6;
    float r = p;
#pragma unroll
    for (int off = 32; off > 0; off >>= 1) r += __shfl_down(r, off);
    if (lane == 0) red[wid] = r;
    __syncthreads();
    if (t == 0) mu_s = (red[0] + red[1] + red[2] + red[3]) * (1.f / 256.f);
    __syncthreads();
    float mu = mu_s;
    float dd = p - mu;
    float r2 = dd * dd;
#pragma unroll
    for (int off = 32; off > 0; off >>= 1) r2 += __shfl_down(r2, off);
    if (lane == 0) red[4 + wid] = r2;
    __syncthreads();
    if (t == 0) var_s = (red[4] + red[5] + red[6] + red[7]) * (1.f / 256.f);
    __syncthreads();

    float ln = dd * (1.0f / sqrtf(var_s + LN_EPS)) * g[t] + beta[t];
    scale[b * DIMC + t] = rintf(fminf(fmaxf(ln, 0.f), 4.f)) * 0.25f;
}

// ---------------------------------------------------------------------------
// K_out: out = fm * scale[b][c]
// ---------------------------------------------------------------------------
__global__ __launch_bounds__(256) void k_out(const float* __restrict__ fm,
                                             const float* __restrict__ scale,
                                             float* __restrict__ out) {
    const size_t total4 = (size_t)BATCH * DIMC * NPIX / 4;
    size_t stride = (size_t)gridDim.x * blockDim.x;
    size_t gid = (size_t)blockIdx.x * blockDim.x + threadIdx.x;
    for (size_t i = gid; i < total4; i += stride) {
        float4 v = *(const float4*)(fm + i * 4);
        float sval = scale[i >> 12];
        float4 o;
        o.x = v.x * sval; o.y = v.y * sval; o.z = v.z * sval; o.w = v.w * sval;
        *(float4*)(out + i * 4) = o;
    }
}

// ---------------------------------------------------------------------------
extern "C" void kernel_launch(void* const* d_in, const int* in_sizes, int n_in,
                              void* d_out, int out_size, void* d_ws, size_t ws_size,
                              hipStream_t stream) {
    (void)in_sizes; (void)n_in; (void)out_size; (void)ws_size;
    const float* fm    = (const float*)d_in[0];
    const float* audio = (const float*)d_in[1];
    const float* Wq    = (const float*)d_in[2];
    const float* Wkv   = (const float*)d_in[3];
    const float* Wp    = (const float*)d_in[4];
    const float* bp    = (const float*)d_in[5];
    const float* g     = (const float*)d_in[6];
    const float* beta  = (const float*)d_in[7];
    float* out = (float*)d_out;

    char* ws = (char*)d_ws;
    float* qkT    = (float*)(ws);                                   // 128 KB
    float* part   = (float*)(ws + (size_t)131072);                  // 2 x 8 MiB
    float* s_part = (float*)(ws + (size_t)131072 + 16777216);       // 512 KB
    float* scale  = (float*)(ws + (size_t)131072 + 16777216 + 524288); // 16 KB
    float* a      = part;   // K_B writes spike output over part[cq=0]

    hipLaunchKernelGGL(k_qk,    dim3(BATCH), dim3(256), 0, stream, audio, Wq, Wkv, qkT);
    hipLaunchKernelGGL(k_attnA, dim3(512),   dim3(256), 0, stream, fm, qkT, part);
    hipLaunchKernelGGL(k_attnB, dim3(2048),  dim3(256), 0, stream, part);
    hipLaunchKernelGGL(k_s,     dim3(1024),  dim3(256), 0, stream, fm, a, s_part);
    hipLaunchKernelGGL(k_scale, dim3(BATCH), dim3(256), 0, stream, s_part, Wkv, Wp, bp, g, beta, scale);
    hipLaunchKernelGGL(k_out,   dim3(2048),  dim3(256), 0, stream, fm, scale, out);
}

// Round 9
// 304.441 us; speedup vs baseline: 1.2545x; 1.0393x over previous
//
#include <hip/hip_runtime.h>
#include <math.h>

#define DIMC 256
#define NH 8
#define NPIX 16384          // 128*128
#define BATCH 16
#define ATT_SCALE 0.17677669529663687f   // 1/sqrt(32)
#define LN_EPS 1e-5f
#define NBLK_S 4            // n-splits in k_s

// ---------------------------------------------------------------------------
// K0: qkT[b][c][h] = SCALE * sum_d q[b][h*32+d] * Wkv[h*32+d][c]
// Layout [c][h] so k_attn can read 8 h contiguously at uniform address.
// ---------------------------------------------------------------------------
__global__ __launch_bounds__(256) void k_qk(const float* __restrict__ audio,
                                            const float* __restrict__ Wq,
                                            const float* __restrict__ Wkv,
                                            float* __restrict__ qkT) {
    int b = blockIdx.x;
    int t = threadIdx.x;
    __shared__ float aud[DIMC];
    __shared__ float qL[DIMC];
    aud[t] = audio[b * DIMC + t];
    __syncthreads();
    {
        const float* wr = Wq + (size_t)t * DIMC;
        float acc = 0.f;
        for (int c = 0; c < DIMC; c += 4) {
            float4 w = *(const float4*)(wr + c);
            acc = fmaf(w.x, aud[c], acc);
            acc = fmaf(w.y, aud[c + 1], acc);
            acc = fmaf(w.z, aud[c + 2], acc);
            acc = fmaf(w.w, aud[c + 3], acc);
        }
        qL[t] = acc;
    }
    __syncthreads();
    {
        int c = t;
        float acc = 0.f;
        for (int i = 0; i < DIMC; ++i) {
            acc = fmaf(qL[i], Wkv[(size_t)i * DIMC + c], acc);
            if ((i & 31) == 31) {
                qkT[((size_t)b * DIMC + c) * NH + (i >> 5)] = ATT_SCALE * acc;
                acc = 0.f;
            }
        }
    }
}

// ---------------------------------------------------------------------------
// K1: attn pass (pure streaming). 512 blocks x 256 thr = 8 waves/CU (2/SIMD).
// Thread owns 2 consecutive n (float2, 512B/wave-instr); loops all 256 c.
// qkT reads are wave-uniform (b, c uniform) -> scalar s_load path, no LDS.
// unroll 8 (was 4): 64 B/lane of fm loads in flight to cover HBM latency.
// a = spike(attn) -> global.
// ---------------------------------------------------------------------------
__global__ __launch_bounds__(256) void k_attn(const float* __restrict__ fm,
                                              const float* __restrict__ qkT,
                                              float* __restrict__ a) {
    int blk  = blockIdx.x;          // 512 = b*32 + nblk
    int b    = blk >> 5;
    int nblk = blk & 31;
    int t    = threadIdx.x;

    const int n0 = nblk * 512 + t * 2;
    const float* fmb = fm + (size_t)b * DIMC * NPIX + n0;
    const float* qb  = qkT + (size_t)b * DIMC * NH;

    float a0[NH], a1[NH];
#pragma unroll
    for (int h = 0; h < NH; ++h) { a0[h] = 0.f; a1[h] = 0.f; }

#pragma unroll 8
    for (int c = 0; c < DIMC; ++c) {
        float2 v  = *(const float2*)(fmb + (size_t)c * NPIX);
        float4 q0 = *(const float4*)(qb + c * NH);       // uniform -> s_load
        float4 q1 = *(const float4*)(qb + c * NH + 4);
        a0[0] = fmaf(v.x, q0.x, a0[0]); a1[0] = fmaf(v.y, q0.x, a1[0]);
        a0[1] = fmaf(v.x, q0.y, a0[1]); a1[1] = fmaf(v.y, q0.y, a1[1]);
        a0[2] = fmaf(v.x, q0.z, a0[2]); a1[2] = fmaf(v.y, q0.z, a1[2]);
        a0[3] = fmaf(v.x, q0.w, a0[3]); a1[3] = fmaf(v.y, q0.w, a1[3]);
        a0[4] = fmaf(v.x, q1.x, a0[4]); a1[4] = fmaf(v.y, q1.x, a1[4]);
        a0[5] = fmaf(v.x, q1.y, a0[5]); a1[5] = fmaf(v.y, q1.y, a1[5]);
        a0[6] = fmaf(v.x, q1.z, a0[6]); a1[6] = fmaf(v.y, q1.z, a1[6]);
        a0[7] = fmaf(v.x, q1.w, a0[7]); a1[7] = fmaf(v.y, q1.w, a1[7]);
    }

#pragma unroll
    for (int h = 0; h < NH; ++h) {
        float2 o;
        o.x = rintf(fminf(fmaxf(a0[h], 0.f), 4.f)) * 0.25f;
        o.y = rintf(fminf(fmaxf(a1[h], 0.f), 4.f)) * 0.25f;
        *(float2*)(a + ((size_t)b * NH + h) * NPIX + n0) = o;
    }
}

// ---------------------------------------------------------------------------
// K2: s partials. 1024 blocks (XCD-bijective swizzle), 256 thr (4 blk/CU).
// Thread = (c_local 16, nq 16): owns one c, strides n by 64.
// ---------------------------------------------------------------------------
__global__ __launch_bounds__(256) void k_s(const float* __restrict__ fm,
                                           const float* __restrict__ a,
                                           float* __restrict__ s_part) {
    int d    = blockIdx.x;
    int blk  = (d & 7) * 128 + (d >> 3);   // bijective: 1024 = 8 x 128
    int b    = blk >> 6;
    int nblk = (blk >> 4) & 3;
    int cblk = blk & 15;
    int t    = threadIdx.x;
    int c_l  = t >> 4;
    int nq   = t & 15;
    int c    = cblk * 16 + c_l;

    const float* fr = fm + ((size_t)b * DIMC + c) * NPIX + nblk * 4096 + nq * 4;
    const float* ab = a + (size_t)b * NH * NPIX + nblk * 4096 + nq * 4;

    float acc[NH];
#pragma unroll
    for (int h = 0; h < NH; ++h) acc[h] = 0.f;

#pragma unroll 2
    for (int j = 0; j < 64; ++j) {
        float4 v = *(const float4*)(fr + j * 64);
#pragma unroll
        for (int h = 0; h < NH; ++h) {
            float4 av = *(const float4*)(ab + (size_t)h * NPIX + j * 64);
            acc[h] += fmaf(v.x, av.x, fmaf(v.y, av.y, fmaf(v.z, av.z, v.w * av.w)));
        }
    }

    __shared__ float red[256 * NH];    // 8 KB
#pragma unroll
    for (int h = 0; h < NH; ++h) red[t * NH + h] = acc[h];
    __syncthreads();

    if (t < 128) {
        int cl = t >> 3, h = t & 7;
        float sum = 0.f;
#pragma unroll
        for (int q = 0; q < 16; ++q)
            sum += red[(cl * 16 + q) * NH + h];
        s_part[(((size_t)b * NBLK_S + nblk) * NH + h) * DIMC + cblk * 16 + cl] = sum;
    }
}

// ---------------------------------------------------------------------------
// K3: s = sum_slab s_part ; x = Wv*s ; p = Wp*x + bp ; LN ; spike -> scale
// ---------------------------------------------------------------------------
__global__ __launch_bounds__(256) void k_scale(const float* __restrict__ s_part,
                                               const float* __restrict__ Wkv,
                                               const float* __restrict__ Wp,
                                               const float* __restrict__ bp,
                                               const float* __restrict__ g,
                                               const float* __restrict__ beta,
                                               float* __restrict__ scale) {
    int b = blockIdx.x;
    int t = threadIdx.x;
    __shared__ float sL[NH][DIMC];
    __shared__ float xL[DIMC];
    __shared__ float red[8];
    __shared__ float mu_s, var_s;

    for (int h = 0; h < NH; ++h) {
        float acc = 0.f;
        for (int sl = 0; sl < NBLK_S; ++sl)
            acc += s_part[(((size_t)b * NBLK_S + sl) * NH + h) * DIMC + t];
        sL[h][t] = acc;
    }
    __syncthreads();

    {
        const float* wr = Wkv + (size_t)(DIMC + t) * DIMC;
        const float* sr = sL[t >> 5];
        float acc = 0.f;
        for (int cc = 0; cc < DIMC; cc += 4) {
            float4 w = *(const float4*)(wr + cc);
            acc = fmaf(w.x, sr[cc], acc);
            acc = fmaf(w.y, sr[cc + 1], acc);
            acc = fmaf(w.z, sr[cc + 2], acc);
            acc = fmaf(w.w, sr[cc + 3], acc);
        }
        xL[t] = acc;
    }
    __syncthreads();

    float p;
    {
        const float* wr = Wp + (size_t)t * DIMC;
        float acc = 0.f;
        for (int i = 0; i < DIMC; i += 4) {
            float4 w = *(const float4*)(wr + i);
            acc = fmaf(w.x, xL[i], acc);
            acc = fmaf(w.y, xL[i + 1], acc);
            acc = fmaf(w.z, xL[i + 2], acc);
            acc = fmaf(w.w, xL[i + 3], acc);
        }
        p = acc + bp[t];
    }

    int lane = t & 63, wid = t >> 6;
    float r = p;
#pragma unroll
    for (int off = 32; off > 0; off >>= 1) r += __shfl_down(r, off);
    if (lane == 0) red[wid] = r;
    __syncthreads();
    if (t == 0) mu_s = (red[0] + red[1] + red[2] + red[3]) * (1.f / 256.f);
    __syncthreads();
    float mu = mu_s;
    float dd = p - mu;
    float r2 = dd * dd;
#pragma unroll
    for (int off = 32; off > 0; off >>= 1) r2 += __shfl_down(r2, off);
    if (lane == 0) red[4 + wid] = r2;
    __syncthreads();
    if (t == 0) var_s = (red[4] + red[5] + red[6] + red[7]) * (1.f / 256.f);
    __syncthreads();

    float ln = dd * (1.0f / sqrtf(var_s + LN_EPS)) * g[t] + beta[t];
    scale[b * DIMC + t] = rintf(fminf(fmaxf(ln, 0.f), 4.f)) * 0.25f;
}

// ---------------------------------------------------------------------------
// K4: out = fm * scale[b][c]
// ---------------------------------------------------------------------------
__global__ __launch_bounds__(256) void k_out(const float* __restrict__ fm,
                                             const float* __restrict__ scale,
                                             float* __restrict__ out) {
    const size_t total4 = (size_t)BATCH * DIMC * NPIX / 4;
    size_t stride = (size_t)gridDim.x * blockDim.x;
    size_t gid = (size_t)blockIdx.x * blockDim.x + threadIdx.x;
    for (size_t i = gid; i < total4; i += stride) {
        float4 v = *(const float4*)(fm + i * 4);
        float sval = scale[i >> 12];
        float4 o;
        o.x = v.x * sval; o.y = v.y * sval; o.z = v.z * sval; o.w = v.w * sval;
        *(float4*)(out + i * 4) = o;
    }
}

// ---------------------------------------------------------------------------
extern "C" void kernel_launch(void* const* d_in, const int* in_sizes, int n_in,
                              void* d_out, int out_size, void* d_ws, size_t ws_size,
                              hipStream_t stream) {
    (void)in_sizes; (void)n_in; (void)out_size; (void)ws_size;
    const float* fm    = (const float*)d_in[0];
    const float* audio = (const float*)d_in[1];
    const float* Wq    = (const float*)d_in[2];
    const float* Wkv   = (const float*)d_in[3];
    const float* Wp    = (const float*)d_in[4];
    const float* bp    = (const float*)d_in[5];
    const float* g     = (const float*)d_in[6];
    const float* beta  = (const float*)d_in[7];
    float* out = (float*)d_out;

    char* ws = (char*)d_ws;
    float* qkT    = (float*)(ws);                                   // 128 KB
    float* a      = (float*)(ws + (size_t)131072);                  // 8 MB
    float* s_part = (float*)(ws + (size_t)131072 + 8388608);        // 512 KB
    float* scale  = (float*)(ws + (size_t)131072 + 8388608 + 524288); // 16 KB

    hipLaunchKernelGGL(k_qk,    dim3(BATCH),      dim3(256), 0, stream, audio, Wq, Wkv, qkT);
    hipLaunchKernelGGL(k_attn,  dim3(512),        dim3(256), 0, stream, fm, qkT, a);
    hipLaunchKernelGGL(k_s,     dim3(1024),       dim3(256), 0, stream, fm, a, s_part);
    hipLaunchKernelGGL(k_scale, dim3(BATCH),      dim3(256), 0, stream, s_part, Wkv, Wp, bp, g, beta, scale);
    hipLaunchKernelGGL(k_out,   dim3(2048),       dim3(256), 0, stream, fm, scale, out);
}